// Round 9
// baseline (227.731 us; speedup 1.0000x reference)
//
#include <hip/hip_runtime.h>
#include <hip/hip_cooperative_groups.h>
#include <math.h>

namespace cg = cooperative_groups;

#define BATCH 32
#define HW 16384
#define WIDTH 128
#define NLINES 1000
#define NCAND 4096
#define CHUNK 1024
#define NCHUNK 4
#define SLOTS_PER_BLOCK 64   // hard bound: max king-graph independent set in 2x128

#define GRID_BLOCKS 512      // 2 blocks/CU on 256 CUs -> cooperative-safe

// Flat output offsets (float elements), reference return order:
// lcmap (32,128,128), lcoff (32,2,128,128), lleng (32,128,128),
// angle (32,128,128), lines (32,1000,2,2), score (32,1000)
#define OFF_LCMAP 0
#define OFF_LCOFF (BATCH * HW)
#define OFF_LLENG (OFF_LCOFF + 2 * BATCH * HW)
#define OFF_ANGLE (OFF_LLENG + BATCH * HW)
#define OFF_LINES (OFF_ANGLE + BATCH * HW)
#define OFF_SCORE (OFF_LINES + BATCH * NLINES * 4)

// Workspace: 32 batches x 4096 u64 keys (no counters, no atomics).
#define WS_NEEDED ((size_t)BATCH * NCAND * 8)

#define PI_F 3.14159265358979323846f

// NMS decomposition: 64 k-tiles of 16, 16 i-splits of 63 (covers 1008 >= 1000)
#define NMS_KTILE 16
#define NMS_NSPLIT 16
#define NMS_SPLIT 63

__device__ __forceinline__ float sigmoidf_(float x) {
    return 1.0f / (1.0f + expf(-x));
}

// Exactly the reference softmax([x0,x1])[1] op sequence (do NOT reformulate
// as sigmoid(x1-x0): ulp-level changes can flip top-k orderings).
__device__ __forceinline__ float softmax1(float x0, float x1) {
    float m = fmaxf(x0, x1);
    float e0 = expf(x0 - m);
    float e1 = expf(x1 - m);
    return e1 / (e0 + e1);
}

__device__ __forceinline__ unsigned long long pack_key(float v, unsigned p) {
    // v > 0 -> float-bit order == value order; inverted index replicates
    // stable lax.top_k tie-breaking (lower index first). Never 0 for a real
    // candidate (low word = ~p != 0), so 0 marks an empty slot.
    return ((unsigned long long)__float_as_uint(v) << 32)
         | (unsigned long long)(0xFFFFFFFFu - p);
}

// Serial keep test on stored lcmap (cold fallback path only).
__device__ bool keep_at(const float* __restrict__ L, int p) {
    int y = p >> 7, x = p & (WIDTH - 1);
    float v = L[p];
    for (int dy = -1; dy <= 1; ++dy) {
        int yy = y + dy;
        if (yy < 0 || yy >= WIDTH) continue;
        for (int dx = -1; dx <= 1; ++dx) {
            if (dy == 0 && dx == 0) continue;
            int xx = x + dx;
            if (xx < 0 || xx >= WIDTH) continue;
            if (L[yy * WIDTH + xx] > v) return false;
        }
    }
    return true;
}

// Single cooperative kernel, 512 blocks x 256 threads, 4 phases split by
// grid.sync(). Each phase keeps the parallelism of the R7 4-kernel layout;
// grid syncs replace 3 kernel launches.
__global__ __launch_bounds__(256) void fused_kernel(
        const float* __restrict__ in, float* __restrict__ out,
        unsigned long long* __restrict__ wskeys) {
    cg::grid_group grid = cg::this_grid();

    __shared__ unsigned long long sk[NCAND];   // 32 KB, multi-purpose
    __shared__ int aux_i[16];
    __shared__ unsigned char flags_s[NMS_KTILE][NMS_NSPLIT];

    const int bid = blockIdx.x;
    const int tid = threadIdx.x;

    // ---------------- Phase A: prep + collect (2048 tiles, 4 per block) ----
    // Tile = 2 rows of one batch. Softmax once per pixel into LDS halo tile;
    // keep-test reads LDS; block-local prefix -> fixed 64-slot key region.
    {
        float (*sm)[WIDTH] = (float (*)[WIDTH])sk;   // [4][128] region
        const int r = tid >> 7;          // 0,1: row within pair
        const int c = tid & (WIDTH - 1);
        const int lane = tid & 63;
        const int w = tid >> 6;
        for (int t = bid; t < BATCH * 64; t += GRID_BLOCKS) {
            const int b = t >> 6;
            const int rp = t & 63;
            const int y0 = rp * 2;
            const int y = y0 + r;
            const int p = y * WIDTH + c;
            const float* __restrict__ ib = in + (size_t)b * 6 * HW;

            float x0 = ib[p];
            float x1 = ib[HW + p];
            float x2 = ib[2 * HW + p];
            float x3 = ib[3 * HW + p];
            float x4 = ib[4 * HW + p];
            float x5 = ib[5 * HW + p];

            float v = softmax1(x0, x1);
            sm[1 + r][c] = v;
            {   // halo rows (clamped)
                int hy = (r == 0) ? (y0 - 1) : (y0 + 2);
                int hyc = min(max(hy, 0), WIDTH - 1);
                int hp = hyc * WIDTH + c;
                sm[r == 0 ? 0 : 3][c] = softmax1(ib[hp], ib[HW + hp]);
            }
            out[OFF_LCMAP + b * HW + p] = v;
            out[OFF_LCOFF + b * 2 * HW + p]      = sigmoidf_(x2) - 0.5f;
            out[OFF_LCOFF + b * 2 * HW + HW + p] = sigmoidf_(x3) - 0.5f;
            out[OFF_LLENG + b * HW + p] = sigmoidf_(x4);
            out[OFF_ANGLE + b * HW + p] = sigmoidf_(x5);
            __syncthreads();

            const int ly = 1 + r;
            float m = -INFINITY;
            #pragma unroll
            for (int dy = -1; dy <= 1; ++dy) {
                #pragma unroll
                for (int dx = -1; dx <= 1; ++dx) {
                    if (dy == 0 && dx == 0) continue;
                    int yy = y + dy, xx = c + dx;
                    int xc = min(max(xx, 0), WIDTH - 1);
                    float nv = sm[ly + dy][xc];
                    bool inb = ((unsigned)yy < (unsigned)WIDTH) & ((unsigned)xx < (unsigned)WIDTH);
                    m = fmaxf(m, inb ? nv : -INFINITY);
                }
            }
            bool keep = (v >= m);

            unsigned long long mask = __ballot(keep);
            if (lane == 0) aux_i[w] = __popcll(mask);
            __syncthreads();
            if (tid == 0) {
                int a0 = aux_i[0], a1 = aux_i[1], a2 = aux_i[2], a3 = aux_i[3];
                aux_i[4] = 0; aux_i[5] = a0; aux_i[6] = a0 + a1; aux_i[7] = a0 + a1 + a2;
                aux_i[8] = a0 + a1 + a2 + a3;
            }
            __syncthreads();

            unsigned long long* __restrict__ gk =
                wskeys + (size_t)b * NCAND + (size_t)rp * SLOTS_PER_BLOCK;
            if (keep) {
                int pos = aux_i[4 + w] + __popcll(mask & ((1ULL << lane) - 1ULL));
                if (pos < SLOTS_PER_BLOCK)   // unreachable for continuous data
                    gk[pos] = pack_key(v, (unsigned)p);
            }
            int tot = aux_i[8] < SLOTS_PER_BLOCK ? aux_i[8] : SLOTS_PER_BLOCK;
            if (tid < SLOTS_PER_BLOCK && tid >= tot)
                gk[tid] = 0ULL;              // zero-fill empty slots
            __syncthreads();                 // before sm/aux reuse next tile
        }
    }
    grid.sync();

    // ---------------- Phase B: sort (blocks 0..127: chunk (b,c)) -----------
    // Sort 1024 keys descending, bitonic, 512 pairs/phase (2 per thread).
    // Chunk is loaded AT ITS FINAL LDS OFFSET so phase C can keep it.
    const int sb = bid >> 2;           // batch for this sort/merge block
    const int sc = bid & 3;            // chunk
    if (bid < NCHUNK * BATCH) {
        unsigned long long* gk = wskeys + (size_t)sb * NCAND;
        const int base = sc * CHUNK;
        for (int i = tid; i < CHUNK; i += 256) sk[base + i] = gk[base + i];
        __syncthreads();
        for (int size = 2; size <= CHUNK; size <<= 1) {
            for (int stride = size >> 1; stride > 0; stride >>= 1) {
                #pragma unroll
                for (int pp = 0; pp < 2; ++pp) {
                    int u = tid + (pp << 8);
                    int il = ((u & ~(stride - 1)) << 1) | (u & (stride - 1));
                    int i = base + il;
                    int j = i | stride;
                    bool asc = (il & size) != 0;
                    unsigned long long a = sk[i], cc = sk[j];
                    if ((a < cc) != asc) { sk[i] = cc; sk[j] = a; }
                }
                __syncthreads();
            }
        }
        for (int i = tid; i < CHUNK; i += 256) gk[base + i] = sk[base + i];
    }
    grid.sync();

    // ---------------- Phase C: merge + lines (blocks 0..127) ---------------
    // Own sorted chunk still in LDS; fetch the other 3; exact rank via 3
    // binary searches (nonzero keys unique); emit lines for rank < 1000.
    if (bid < NCHUNK * BATCH) {
        const unsigned long long* gk = wskeys + (size_t)sb * NCAND;
        #pragma unroll
        for (int c2 = 0; c2 < NCHUNK; ++c2) {
            if (c2 == sc) continue;
            for (int i = tid; i < CHUNK; i += 256)
                sk[c2 * CHUNK + i] = gk[c2 * CHUNK + i];
        }
        __syncthreads();

        const float* off0 = out + OFF_LCOFF + sb * 2 * HW;
        const float* off1 = off0 + HW;
        const float* leng = out + OFF_LLENG + sb * HW;
        const float* ang  = out + OFF_ANGLE + sb * HW;

        #pragma unroll
        for (int q = 0; q < CHUNK / 256; ++q) {
            int lslot = q * 256 + tid;
            unsigned long long e = sk[sc * CHUNK + lslot];
            if (e == 0ULL) continue;
            int rank = lslot;
            #pragma unroll
            for (int c2 = 0; c2 < NCHUNK; ++c2) {
                if (c2 == sc) continue;
                const unsigned long long* A = sk + c2 * CHUNK;
                int lo = 0, hi = CHUNK;
                while (lo < hi) {
                    int mid = (lo + hi) >> 1;
                    if (A[mid] > e) lo = mid + 1; else hi = mid;
                }
                rank += lo;
            }
            if (rank < NLINES) {
                unsigned p = 0xFFFFFFFFu - (unsigned)(e & 0xFFFFFFFFull);
                float score = __uint_as_float((unsigned)(e >> 32));
                int yi = (int)(p >> 7), xi = (int)(p & (WIDTH - 1));
                float yc = (float)yi + off0[p] + 0.5f;
                float xc = (float)xi + off1[p] + 0.5f;
                float hl = leng[p] * 64.0f;          // RESOLUTION/2
                float th = ang[p] * PI_F;
                float dy = hl * sinf(th);
                float dx = hl * cosf(th);
                float4 ln = make_float4(yc - dy, xc - dx, yc + dy, xc + dx);
                *(float4*)(out + OFF_LINES + (size_t)(sb * NLINES + rank) * 4) = ln;
                out[OFF_SCORE + sb * NLINES + rank] = score;
            }
        }

        // Fallback (never triggers): pad ranks [cnt,1000) with lowest
        // non-kept flat indices, score 0. Chunk-0 block owns it.
        if (sc == 0) {
            int local = 0;
            for (int i = tid; i < NCAND; i += 256) local += (sk[i] != 0ULL);
            for (int off = 32; off; off >>= 1) local += __shfl_down(local, off);
            if ((tid & 63) == 0) aux_i[tid >> 6] = local;
            __syncthreads();
            if (tid == 0) {
                int cnt = aux_i[0] + aux_i[1] + aux_i[2] + aux_i[3];
                if (cnt < NLINES) {
                    const float* L = out + OFF_LCMAP + sb * HW;
                    int rank = cnt;
                    for (int p = 0; p < HW && rank < NLINES; ++p) {
                        if (keep_at(L, p)) continue;
                        int yi = p >> 7, xi = p & (WIDTH - 1);
                        float yc = (float)yi + off0[p] + 0.5f;
                        float xc = (float)xi + off1[p] + 0.5f;
                        float hl = leng[p] * 64.0f;
                        float th = ang[p] * PI_F;
                        float dy = hl * sinf(th);
                        float dx = hl * cosf(th);
                        float* lo = out + OFF_LINES + (size_t)(sb * NLINES + rank) * 4;
                        lo[0] = yc - dy; lo[1] = xc - dx; lo[2] = yc + dy; lo[3] = xc + dx;
                        out[OFF_SCORE + sb * NLINES + rank] = 0.0f;
                        ++rank;
                    }
                }
            }
        }
    }
    grid.sync();

    // ---------------- Phase D: structure NMS (2048 tasks, 4 per block) -----
    // Task = (k-tile of 16, batch); block 256 = 16 k x 16 i-splits of 63.
    // __f*_rn forbids fma contraction (dist must match reference rounding).
    {
        float4* lsv = (float4*)sk;                   // [1000] region, 16 KB
        const int kl = tid & (NMS_KTILE - 1);
        const int s  = tid >> 4;
        for (int t = bid; t < 64 * BATCH; t += GRID_BLOCKS) {
            const int tile = t & 63;
            const int b = t >> 6;
            const float4* lg = (const float4*)(out + OFF_LINES + (size_t)b * NLINES * 4);
            for (int i = tid; i < NLINES; i += 256) lsv[i] = lg[i];
            __syncthreads();

            const int k = tile * NMS_KTILE + kl;
            float4 P = lsv[k < NLINES ? k : 0];
            int istart = s * NMS_SPLIT;
            int iend = min(NMS_SPLIT * (s + 1), min(k, NLINES));
            bool sup = false;
            for (int i = istart; i < iend; ++i) {
                float4 Q = lsv[i];
                float a1 = __fadd_rn(__fmul_rn(Q.x - P.x, Q.x - P.x),
                                     __fmul_rn(Q.y - P.y, Q.y - P.y));
                float a2 = __fadd_rn(__fmul_rn(Q.z - P.z, Q.z - P.z),
                                     __fmul_rn(Q.w - P.w, Q.w - P.w));
                float d1 = __fadd_rn(a1, a2);
                float b1 = __fadd_rn(__fmul_rn(Q.x - P.z, Q.x - P.z),
                                     __fmul_rn(Q.y - P.w, Q.y - P.w));
                float b2 = __fadd_rn(__fmul_rn(Q.z - P.x, Q.z - P.x),
                                     __fmul_rn(Q.w - P.y, Q.w - P.y));
                float d2 = __fadd_rn(b1, b2);
                sup |= (fminf(d1, d2) <= 2.0f);
            }
            flags_s[kl][s] = (unsigned char)sup;
            __syncthreads();

            if (s == 0 && k < NLINES) {
                int any = 0;
                #pragma unroll
                for (int i = 0; i < NMS_NSPLIT; ++i) any |= flags_s[kl][i];
                float sc2 = out[OFF_SCORE + b * NLINES + k];
                out[OFF_SCORE + b * NLINES + k] = any ? 0.0f : sc2;
            }
        }
    }
}

extern "C" void kernel_launch(void* const* d_in, const int* in_sizes, int n_in,
                              void* d_out, int out_size, void* d_ws, size_t ws_size,
                              hipStream_t stream) {
    const float* in = (const float*)d_in[0];
    float* out = (float*)d_out;
    (void)in_sizes; (void)n_in; (void)out_size;

    if (d_ws == nullptr || ws_size < WS_NEEDED) return;
    unsigned long long* wskeys = (unsigned long long*)d_ws;

    void* kargs[] = { (void*)&in, (void*)&out, (void*)&wskeys };
    hipLaunchCooperativeKernel((void*)fused_kernel, dim3(GRID_BLOCKS), dim3(256),
                               kargs, 0, stream);
}

// Round 10
// 43.192 us; speedup vs baseline: 5.2725x; 5.2725x over previous
//
#include <hip/hip_runtime.h>
#include <math.h>

#define BATCH 32
#define HW 16384
#define WIDTH 128
#define NLINES 1000
#define NCAND 4096
#define NCH 8                 // chunks per batch
#define CHSZ 512              // keys per chunk = max independent set in 16x128

// Flat output offsets (float elements), reference return order:
// lcmap (32,128,128), lcoff (32,2,128,128), lleng (32,128,128),
// angle (32,128,128), lines (32,1000,2,2), score (32,1000)
#define OFF_LCMAP 0
#define OFF_LCOFF (BATCH * HW)
#define OFF_LLENG (OFF_LCOFF + 2 * BATCH * HW)
#define OFF_ANGLE (OFF_LLENG + BATCH * HW)
#define OFF_LINES (OFF_ANGLE + BATCH * HW)
#define OFF_SCORE (OFF_LINES + BATCH * NLINES * 4)

// Workspace: 32 batches x 4096 u64 keys.
#define WS_NEEDED ((size_t)BATCH * NCAND * 8)

#define PI_F 3.14159265358979323846f

// NMS decomposition: 64 k-tiles of 16, 16 i-splits of 63 (covers 1008 >= 1000)
#define NMS_KTILE 16
#define NMS_NSPLIT 16
#define NMS_SPLIT 63

__device__ __forceinline__ float sigmoidf_(float x) {
    return 1.0f / (1.0f + expf(-x));
}

// Exactly the reference softmax([x0,x1])[1] op sequence (do NOT reformulate
// as sigmoid(x1-x0): ulp-level changes can flip top-k orderings).
__device__ __forceinline__ float softmax1(float x0, float x1) {
    float m = fmaxf(x0, x1);
    float e0 = expf(x0 - m);
    float e1 = expf(x1 - m);
    return e1 / (e0 + e1);
}

__device__ __forceinline__ unsigned long long pack_key(float v, unsigned p) {
    // v > 0 -> float-bit order == value order; inverted index replicates
    // stable lax.top_k tie-breaking (lower index first). Never 0 for a real
    // candidate (low word = ~p != 0), so 0 marks an empty slot.
    return ((unsigned long long)__float_as_uint(v) << 32)
         | (unsigned long long)(0xFFFFFFFFu - p);
}

// K1: prep (float4-vectorized) + local-max collect + in-LDS bitonic sort of
// the block's own 512-key chunk. Grid (8 chunks, 32 batches) = 256 blocks x
// 512 threads; block tile = 16 rows x 128 cols, 4 px/thread.
__global__ __launch_bounds__(512) void prep_sort_kernel(
        const float* __restrict__ in, float* __restrict__ out,
        unsigned long long* __restrict__ wskeys) {
    __shared__ float sm[18][WIDTH];              // rows y0-1 .. y0+16 (9 KB)
    __shared__ unsigned long long skeys[CHSZ];   // 4 KB
    __shared__ int wcnt[8], wpre[8], tot_s;

    const int c = blockIdx.x;        // chunk (16-row band)
    const int b = blockIdx.y;        // batch
    const int tid = threadIdx.x;
    const int r = tid >> 5;          // row in tile 0..15
    const int xq = tid & 31;         // quad index in row
    const int x0 = xq * 4;
    const int y0 = c * 16;
    const int y = y0 + r;
    const int p = y * WIDTH + x0;

    const float4* __restrict__ ib4 =
        (const float4*)(in + (size_t)b * 6 * HW);
    const int q = y * 32 + xq;

    float4 f0 = ib4[q];
    float4 f1 = ib4[4096 + q];
    float4 f2 = ib4[2 * 4096 + q];
    float4 f3 = ib4[3 * 4096 + q];
    float4 f4 = ib4[4 * 4096 + q];
    float4 f5 = ib4[5 * 4096 + q];

    float4 v;
    v.x = softmax1(f0.x, f1.x); v.y = softmax1(f0.y, f1.y);
    v.z = softmax1(f0.z, f1.z); v.w = softmax1(f0.w, f1.w);
    sm[1 + r][x0] = v.x; sm[1 + r][x0 + 1] = v.y;
    sm[1 + r][x0 + 2] = v.z; sm[1 + r][x0 + 3] = v.w;

    // Halo rows (clamped copies; out-of-bounds excluded by inb mask later).
    if (tid < 64) {
        int top = (tid < 32);
        int hy = top ? max(y0 - 1, 0) : min(y0 + 16, WIDTH - 1);
        int hxq = tid & 31;
        int hq = hy * 32 + hxq;
        float4 h0 = ib4[hq], h1 = ib4[4096 + hq];
        int row = top ? 0 : 17;
        int hx = hxq * 4;
        sm[row][hx]     = softmax1(h0.x, h1.x);
        sm[row][hx + 1] = softmax1(h0.y, h1.y);
        sm[row][hx + 2] = softmax1(h0.z, h1.z);
        sm[row][hx + 3] = softmax1(h0.w, h1.w);
    }

    // Vectorized elementwise outputs.
    float4* __restrict__ o4 = (float4*)out;
    o4[b * 4096 + q] = v;
    float4 c0, c1, le, an;
    c0.x = sigmoidf_(f2.x) - 0.5f; c0.y = sigmoidf_(f2.y) - 0.5f;
    c0.z = sigmoidf_(f2.z) - 0.5f; c0.w = sigmoidf_(f2.w) - 0.5f;
    c1.x = sigmoidf_(f3.x) - 0.5f; c1.y = sigmoidf_(f3.y) - 0.5f;
    c1.z = sigmoidf_(f3.z) - 0.5f; c1.w = sigmoidf_(f3.w) - 0.5f;
    le.x = sigmoidf_(f4.x); le.y = sigmoidf_(f4.y);
    le.z = sigmoidf_(f4.z); le.w = sigmoidf_(f4.w);
    an.x = sigmoidf_(f5.x); an.y = sigmoidf_(f5.y);
    an.z = sigmoidf_(f5.z); an.w = sigmoidf_(f5.w);
    o4[OFF_LCOFF / 4 + b * 8192 + q] = c0;
    o4[OFF_LCOFF / 4 + b * 8192 + 4096 + q] = c1;
    o4[OFF_LLENG / 4 + b * 4096 + q] = le;
    o4[OFF_ANGLE / 4 + b * 4096 + q] = an;
    __syncthreads();

    // keep test per pixel (LDS reads); inb mask uses global coords.
    bool keep[4];
    const float vv[4] = { v.x, v.y, v.z, v.w };
    #pragma unroll
    for (int j = 0; j < 4; ++j) {
        int xx0 = x0 + j;
        float m = -INFINITY;
        #pragma unroll
        for (int dy = -1; dy <= 1; ++dy) {
            #pragma unroll
            for (int dx = -1; dx <= 1; ++dx) {
                if (dy == 0 && dx == 0) continue;
                int yy = y + dy, xx = xx0 + dx;
                int xc = min(max(xx, 0), WIDTH - 1);
                float nv = sm[1 + r + dy][xc];
                bool inb = ((unsigned)yy < (unsigned)WIDTH) &
                           ((unsigned)xx < (unsigned)WIDTH);
                m = fmaxf(m, inb ? nv : -INFINITY);
            }
        }
        keep[j] = (vv[j] >= m);
    }

    // Block-local compaction (order within chunk irrelevant: sorted next).
    const int lane = tid & 63;
    const int wv = tid >> 6;
    unsigned long long mask[4];
    #pragma unroll
    for (int j = 0; j < 4; ++j) mask[j] = __ballot(keep[j]);
    int cw = __popcll(mask[0]) + __popcll(mask[1]) +
             __popcll(mask[2]) + __popcll(mask[3]);
    if (lane == 0) wcnt[wv] = cw;
    __syncthreads();
    if (tid == 0) {
        int acc = 0;
        #pragma unroll
        for (int i = 0; i < 8; ++i) { wpre[i] = acc; acc += wcnt[i]; }
        tot_s = acc;
    }
    __syncthreads();

    {
        int base = wpre[wv];
        unsigned long long below = (lane == 63) ? ~0ULL >> 1 : ((1ULL << lane) - 1ULL);
        below = (1ULL << lane) - 1ULL;   // lane<64 -> safe shift pattern below
        int before = 0;
        #pragma unroll
        for (int j = 0; j < 4; ++j) {
            if (keep[j]) {
                int pos = base + before +
                          (int)__popcll(mask[j] & ((lane == 0) ? 0ULL : (~0ULL >> (64 - lane))));
                if (pos < CHSZ)          // tie-plateau guard (unreachable)
                    skeys[pos] = pack_key(vv[j], (unsigned)(p + j));
            }
            before += (int)__popcll(mask[j]);
        }
    }
    int tot = tot_s < CHSZ ? tot_s : CHSZ;
    if (tid < CHSZ && tid >= tot) skeys[tid] = 0ULL;
    __syncthreads();

    // Bitonic sort 512 keys, descending (256 pairs/phase, threads < 256).
    for (int size = 2; size <= CHSZ; size <<= 1) {
        for (int stride = size >> 1; stride > 0; stride >>= 1) {
            if (tid < 256) {
                int u = tid;
                int il = ((u & ~(stride - 1)) << 1) | (u & (stride - 1));
                int i = il, j = il | stride;
                bool asc = (il & size) != 0;
                unsigned long long a = skeys[i], cc = skeys[j];
                if ((a < cc) != asc) { skeys[i] = cc; skeys[j] = a; }
            }
            __syncthreads();
        }
    }

    unsigned long long* __restrict__ gk =
        wskeys + (size_t)b * NCAND + (size_t)c * CHSZ;
    if (tid < CHSZ) gk[tid] = skeys[tid];
}

// Serial keep test on stored lcmap (cold fallback path only).
__device__ bool keep_at(const float* __restrict__ L, int p) {
    int y = p >> 7, x = p & (WIDTH - 1);
    float v = L[p];
    for (int dy = -1; dy <= 1; ++dy) {
        int yy = y + dy;
        if (yy < 0 || yy >= WIDTH) continue;
        for (int dx = -1; dx <= 1; ++dx) {
            if (dy == 0 && dx == 0) continue;
            int xx = x + dx;
            if (xx < 0 || xx >= WIDTH) continue;
            if (L[yy * WIDTH + xx] > v) return false;
        }
    }
    return true;
}

// K2: merge 8 sorted 512-chunks by exact rank (7 binary searches; nonzero
// keys unique), emit lines+scores for rank < 1000. Grid (8,32) x 512 thr.
// Chunk-0 block owns the never-triggering cnt<1000 zero-pad fallback.
__global__ __launch_bounds__(512) void merge_lines_kernel(
        float* __restrict__ out, const unsigned long long* __restrict__ wskeys) {
    __shared__ unsigned long long sk[NCAND];   // 32 KB
    __shared__ int wsum[8];
    const int c = blockIdx.x, b = blockIdx.y;
    const unsigned long long* gk = wskeys + (size_t)b * NCAND;
    for (int i = threadIdx.x; i < NCAND; i += 512) sk[i] = gk[i];
    __syncthreads();

    const float* off0 = out + OFF_LCOFF + b * 2 * HW;
    const float* off1 = off0 + HW;
    const float* leng = out + OFF_LLENG + b * HW;
    const float* ang  = out + OFF_ANGLE + b * HW;

    unsigned long long e = sk[c * CHSZ + threadIdx.x];
    if (e != 0ULL) {
        int rank = threadIdx.x;              // local rank in own chunk
        #pragma unroll
        for (int c2 = 0; c2 < NCH; ++c2) {
            if (c2 == c) continue;
            const unsigned long long* A = sk + c2 * CHSZ;
            int lo = 0, hi = CHSZ;
            while (lo < hi) {
                int mid = (lo + hi) >> 1;
                if (A[mid] > e) lo = mid + 1; else hi = mid;
            }
            rank += lo;                      // keys > e in c2
        }
        if (rank < NLINES) {
            unsigned p = 0xFFFFFFFFu - (unsigned)(e & 0xFFFFFFFFull);
            float score = __uint_as_float((unsigned)(e >> 32));
            int yi = (int)(p >> 7), xi = (int)(p & (WIDTH - 1));
            float yc = (float)yi + off0[p] + 0.5f;
            float xc = (float)xi + off1[p] + 0.5f;
            float hl = leng[p] * 64.0f;      // RESOLUTION/2
            float th = ang[p] * PI_F;
            float dy = hl * sinf(th);
            float dx = hl * cosf(th);
            float4 ln = make_float4(yc - dy, xc - dx, yc + dy, xc + dx);
            *(float4*)(out + OFF_LINES + (size_t)(b * NLINES + rank) * 4) = ln;
            out[OFF_SCORE + b * NLINES + rank] = score;
        }
    }

    // Fallback (never triggers): pad ranks [cnt,1000) with lowest non-kept
    // flat indices, score 0. Disjoint ranks -> race-free vs other blocks.
    if (c != 0) return;
    int local = 0;
    for (int i = threadIdx.x; i < NCAND; i += 512) local += (sk[i] != 0ULL);
    for (int off = 32; off; off >>= 1) local += __shfl_down(local, off);
    if ((threadIdx.x & 63) == 0) wsum[threadIdx.x >> 6] = local;
    __syncthreads();
    if (threadIdx.x != 0) return;
    int cnt = 0;
    #pragma unroll
    for (int i = 0; i < 8; ++i) cnt += wsum[i];
    if (cnt >= NLINES) return;
    const float* L = out + OFF_LCMAP + b * HW;
    int rank = cnt;
    for (int p = 0; p < HW && rank < NLINES; ++p) {
        if (keep_at(L, p)) continue;
        int yi = p >> 7, xi = p & (WIDTH - 1);
        float yc = (float)yi + off0[p] + 0.5f;
        float xc = (float)xi + off1[p] + 0.5f;
        float hl = leng[p] * 64.0f;
        float th = ang[p] * PI_F;
        float dy = hl * sinf(th);
        float dx = hl * cosf(th);
        float* lo = out + OFF_LINES + (size_t)(b * NLINES + rank) * 4;
        lo[0] = yc - dy; lo[1] = xc - dx; lo[2] = yc + dy; lo[3] = xc + dx;
        out[OFF_SCORE + b * NLINES + rank] = 0.0f;
        ++rank;
    }
}

// K3: structure NMS. Grid (64 k-tiles, 32 batches), block 256 =
// 16 k x 16 i-splits of 63 -> max 63 iters/lane, 2048 blocks load-balance.
// __f*_rn intrinsics forbid fma contraction so dist matches reference rounding.
__global__ __launch_bounds__(256) void nms_kernel(float* __restrict__ out) {
    __shared__ float4 lsv[NLINES];               // 16 KB
    __shared__ unsigned char flags[NMS_KTILE][NMS_NSPLIT];
    const int tile = blockIdx.x, b = blockIdx.y;
    const float4* lg = (const float4*)(out + OFF_LINES + (size_t)b * NLINES * 4);
    for (int i = threadIdx.x; i < NLINES; i += 256) lsv[i] = lg[i];
    __syncthreads();

    const int kl = threadIdx.x & (NMS_KTILE - 1);
    const int s  = threadIdx.x >> 4;             // i-range split 0..15
    const int k  = tile * NMS_KTILE + kl;
    float4 P = lsv[k < NLINES ? k : 0];

    int istart = s * NMS_SPLIT;
    int iend = min(NMS_SPLIT * (s + 1), min(k, NLINES));
    bool sup = false;
    for (int i = istart; i < iend; ++i) {
        float4 Q = lsv[i];
        float a1 = __fadd_rn(__fmul_rn(Q.x - P.x, Q.x - P.x),
                             __fmul_rn(Q.y - P.y, Q.y - P.y));
        float a2 = __fadd_rn(__fmul_rn(Q.z - P.z, Q.z - P.z),
                             __fmul_rn(Q.w - P.w, Q.w - P.w));
        float d1 = __fadd_rn(a1, a2);
        float b1 = __fadd_rn(__fmul_rn(Q.x - P.z, Q.x - P.z),
                             __fmul_rn(Q.y - P.w, Q.y - P.w));
        float b2 = __fadd_rn(__fmul_rn(Q.z - P.x, Q.z - P.x),
                             __fmul_rn(Q.w - P.y, Q.w - P.y));
        float d2 = __fadd_rn(b1, b2);
        sup |= (fminf(d1, d2) <= 2.0f);
    }
    flags[kl][s] = (unsigned char)sup;
    __syncthreads();

    if (s == 0 && k < NLINES) {
        int any = 0;
        #pragma unroll
        for (int i = 0; i < NMS_NSPLIT; ++i) any |= flags[kl][i];
        float sc = out[OFF_SCORE + b * NLINES + k];
        out[OFF_SCORE + b * NLINES + k] = any ? 0.0f : sc;
    }
}

extern "C" void kernel_launch(void* const* d_in, const int* in_sizes, int n_in,
                              void* d_out, int out_size, void* d_ws, size_t ws_size,
                              hipStream_t stream) {
    const float* in = (const float*)d_in[0];
    float* out = (float*)d_out;
    (void)in_sizes; (void)n_in; (void)out_size;

    if (d_ws == nullptr || ws_size < WS_NEEDED) return;
    unsigned long long* wskeys = (unsigned long long*)d_ws;

    prep_sort_kernel<<<dim3(NCH, BATCH), 512, 0, stream>>>(in, out, wskeys);
    merge_lines_kernel<<<dim3(NCH, BATCH), 512, 0, stream>>>(out, wskeys);
    nms_kernel<<<dim3(64, BATCH), 256, 0, stream>>>(out);
}